// Round 4
// baseline (102.137 us; speedup 1.0000x reference)
//
#include <hip/hip_runtime.h>

// out[b] = P @ X[b] @ P^T where P (7140x1024) is 0/1 with exactly one 1 per
// column => pure scatter: out[b][r(i)][r(j)] = X[b][i][j], zeros elsewhere.
// Row-oriented + NON-TEMPORAL stores (nt flag bypasses L2 allocation,
// matching the runtime fill kernel's ~6.9 TB/s vs 4.4 TB/s through-cache).

constexpr int D_IN   = 1024;
constexpr int D_OUT  = 7140;          // C(36,3)
constexpr int VROW   = D_OUT / 4;     // 1785 float4 per output row
constexpr int NQ     = 36;
constexpr int NROWS  = 2 * D_OUT;     // batch=2

typedef float f32x4 __attribute__((ext_vector_type(4)));   // native vector: nt-store OK

__global__ __launch_bounds__(256) void sandwich_rows_nt_kernel(
    const float* __restrict__ in, float* __restrict__ out)
{
    __shared__ __align__(16) short inv[D_OUT];   // out row/col -> in idx, or -1
    __shared__ __align__(16) float srow[D_IN];   // staged source row

    for (int t = threadIdx.x; t < D_OUT; t += blockDim.x) inv[t] = -1;
    __syncthreads();
    for (int t = threadIdx.x; t < D_IN; t += blockDim.x) {
        int ch   = t & 3;
        int col  = (t >> 2) & 15;
        int line = t >> 6;
        int a = line, b = 16 + col, c = 32 + ch;
        int r = 0;
        for (int x = 0; x < a; ++x) r += (NQ - 1 - x) * (NQ - 2 - x) / 2;
        for (int y = a + 1; y < b; ++y) r += NQ - 1 - y;
        r += c - b - 1;
        inv[r] = (short)t;
    }
    __syncthreads();

    for (int row = blockIdx.x; row < NROWS; row += gridDim.x) {
        int o = row, bb = 0;
        if (o >= D_OUT) { o -= D_OUT; bb = 1; }

        f32x4* __restrict__ orow = reinterpret_cast<f32x4*>(out) + (size_t)row * VROW;
        int io = inv[o];                       // block-uniform

        if (io < 0) {
            const f32x4 z = (f32x4)(0.f);
            for (int p = threadIdx.x; p < VROW; p += blockDim.x)
                __builtin_nontemporal_store(z, &orow[p]);
        } else {
            const f32x4* __restrict__ srcv = reinterpret_cast<const f32x4*>(
                in + (size_t)bb * (D_IN * D_IN) + (size_t)io * D_IN);
            if (threadIdx.x < D_IN / 4)
                reinterpret_cast<f32x4*>(srow)[threadIdx.x] = srcv[threadIdx.x];
            __syncthreads();

            for (int p = threadIdx.x; p < VROW; p += blockDim.x) {
                short4 iv = *reinterpret_cast<const short4*>(&inv[p * 4]);
                f32x4 v;
                v.x = (iv.x >= 0) ? srow[iv.x] : 0.f;
                v.y = (iv.y >= 0) ? srow[iv.y] : 0.f;
                v.z = (iv.z >= 0) ? srow[iv.z] : 0.f;
                v.w = (iv.w >= 0) ? srow[iv.w] : 0.f;
                __builtin_nontemporal_store(v, &orow[p]);
            }
            __syncthreads();   // srow reused next row (block-uniform branch, safe)
        }
    }
}

extern "C" void kernel_launch(void* const* d_in, const int* in_sizes, int n_in,
                              void* d_out, int out_size, void* d_ws, size_t ws_size,
                              hipStream_t stream) {
    const float* in = (const float*)d_in[0];   // (2, 1024, 1024) f32
    float* out = (float*)d_out;                // (2, 7140, 7140) f32

    dim3 grid(2048), block(256);
    hipLaunchKernelGGL(sandwich_rows_nt_kernel, grid, block, 0, stream, in, out);
}

// Round 5
// 84.379 us; speedup vs baseline: 1.2105x; 1.2105x over previous
//
#include <hip/hip_runtime.h>

// out[b] = P @ X[b] @ P^T, P (7140x1024) 0/1 with one 1 per column => scatter:
// out[b][rank(i)][rank(j)] = X[b][i][j], zeros elsewhere.
// Split: A = pure zero-fill clone of rocclr fillBufferAligned (tests 7 TB/s
// store path); B = scatter the 2 x 1024 x 1024 data elements (consecutive-in-ch
// ranks => one unaligned float4 store per lane). Stream order A -> B.

constexpr int D_IN  = 1024;
constexpr int D_OUT = 7140;            // C(36,3)

typedef float f32x4 __attribute__((ext_vector_type(4)));
typedef f32x4 f32x4u __attribute__((aligned(4)));   // 4B-aligned 16B store

// rank of (a, b, c), 0<=a<b<c<36, among C(36,3) combinations (closed form)
__device__ __forceinline__ int rank36_3(int a, int b, int c) {
    int s1 = 7140 - (36 - a) * (35 - a) * (34 - a) / 6;          // sum over x<a
    int s2 = ((34 - a) * (35 - a) - (35 - b) * (36 - b)) / 2;    // sum a<y<b
    return s1 + s2 + (c - b - 1);
}

// ---- Kernel A: memset-shaped zero fill, one-shot grid, 4 stores/thread ----
__global__ __launch_bounds__(256) void zero_fill_kernel(f32x4* __restrict__ out, int nvec)
{
    const f32x4 z = (f32x4)(0.f);
    int base = blockIdx.x * 1024 + threadIdx.x;      // 256 threads * 4 vec
    if (base + 768 < nvec) {
        out[base]       = z;
        out[base + 256] = z;
        out[base + 512] = z;
        out[base + 768] = z;
    } else {
        #pragma unroll
        for (int k = 0; k < 4; ++k) {
            int i = base + k * 256;
            if (i < nvec) out[i] = z;
        }
    }
}

// ---- Kernel B: one block per data row; coalesced read, rank-scatter store ----
__global__ __launch_bounds__(256) void scatter_rows_kernel(
    const float* __restrict__ in, float* __restrict__ out)
{
    const int bb = blockIdx.x >> 10;         // batch
    const int t  = blockIdx.x & 1023;        // source row index i

    // output row = rank of source row's combination (block-uniform)
    const int o = rank36_3(t >> 6, 16 + ((t >> 2) & 15), 32 + (t & 3));

    // lane handles source columns j0..j0+3 (same line/col, ch=0..3
    // => 4 consecutive output columns starting at rank(line,16+col,32))
    const int j0   = threadIdx.x * 4;
    const int line = j0 >> 6;
    const int col  = (j0 >> 2) & 15;
    const int c0   = rank36_3(line, 16 + col, 32);

    const f32x4 v = *reinterpret_cast<const f32x4*>(
        in + (size_t)bb * (D_IN * D_IN) + (size_t)t * D_IN + j0);

    float* __restrict__ orow = out + ((size_t)bb * D_OUT + o) * D_OUT;
    *reinterpret_cast<f32x4u*>(orow + c0) = v;
}

extern "C" void kernel_launch(void* const* d_in, const int* in_sizes, int n_in,
                              void* d_out, int out_size, void* d_ws, size_t ws_size,
                              hipStream_t stream) {
    const float* in = (const float*)d_in[0];   // (2, 1024, 1024) f32
    float* out = (float*)d_out;                // (2, 7140, 7140) f32

    int nvec = out_size / 4;                   // 25,489,800 float4 slots
    int gridA = (nvec + 1023) / 1024;          // 24,893 one-shot blocks

    hipLaunchKernelGGL(zero_fill_kernel, dim3(gridA), dim3(256), 0, stream,
                       reinterpret_cast<f32x4*>(out), nvec);
    hipLaunchKernelGGL(scatter_rows_kernel, dim3(2 * D_IN), dim3(256), 0, stream,
                       in, out);
}